// Round 1
// baseline (90.696 us; speedup 1.0000x reference)
//
#include <hip/hip_runtime.h>

#define LOG2E 1.4426950408889634f

typedef __bf16 bf16x8 __attribute__((ext_vector_type(8)));
typedef float  f32x4  __attribute__((ext_vector_type(4)));

__device__ inline unsigned short f2bf(float f){
  unsigned u = __float_as_uint(f);
  unsigned r = u + 0x7FFFu + ((u >> 16) & 1u);   // RNE; inputs are finite randoms
  return (unsigned short)(r >> 16);
}

// ---- K0a: x [256][1024] f32 -> xb bf16 (same row-major layout) ----
__global__ __launch_bounds__(256) void k_cvt_x(const float* __restrict__ x,
                                               unsigned short* __restrict__ xb){
  int t = blockIdx.x * 256 + threadIdx.x;         // 32768 threads * 8 elems
  const float4* x4 = (const float4*)x;
  float4 a = x4[t * 2], b = x4[t * 2 + 1];
  uint4 o;
  o.x = f2bf(a.x) | ((unsigned)f2bf(a.y) << 16);
  o.y = f2bf(a.z) | ((unsigned)f2bf(a.w) << 16);
  o.z = f2bf(b.x) | ((unsigned)f2bf(b.y) << 16);
  o.w = f2bf(b.z) | ((unsigned)f2bf(b.w) << 16);
  ((uint4*)xb)[t] = o;
}

// ---- K0b: W [1024][1024] f32 (k-major) -> Wt [1024][1024] bf16 (n-major, i.e. W^T) ----
__global__ __launch_bounds__(256) void k_tr_w(const float* __restrict__ W,
                                              unsigned short* __restrict__ Wt){
  __shared__ unsigned short T[64 * 72];           // T[n_local][k_local], pad 72
  int kt = blockIdx.x * 64, nt = blockIdx.y * 64;
  int t = threadIdx.x;
  int col4 = t & 15;                              // n_local group = col4*4 + e
  int g = t >> 4;                                 // 0..15
  #pragma unroll
  for (int s = 0; s < 2; ++s){
    int k0 = 2 * (g + 16 * s);                    // even k row pairs
    float4 a = *((const float4*)(W + (size_t)(kt + k0    ) * 1024 + nt) + col4);
    float4 b = *((const float4*)(W + (size_t)(kt + k0 + 1) * 1024 + nt) + col4);
    *(unsigned*)(&T[(col4*4+0)*72 + k0]) = f2bf(a.x) | ((unsigned)f2bf(b.x) << 16);
    *(unsigned*)(&T[(col4*4+1)*72 + k0]) = f2bf(a.y) | ((unsigned)f2bf(b.y) << 16);
    *(unsigned*)(&T[(col4*4+2)*72 + k0]) = f2bf(a.z) | ((unsigned)f2bf(b.z) << 16);
    *(unsigned*)(&T[(col4*4+3)*72 + k0]) = f2bf(a.w) | ((unsigned)f2bf(b.w) << 16);
  }
  __syncthreads();
  int nl = t >> 2;                                // 0..63
  int kq = t & 3;                                 // 16-elem chunk
  uint4* dst = (uint4*)(Wt + (size_t)(nt + nl) * 1024 + kt + kq * 16);
  const uint4* src = (const uint4*)(&T[nl * 72 + kq * 16]);
  dst[0] = src[0];
  dst[1] = src[1];
}

// ---- K1: mat[256][1024] f32 = xb[256][1024] * Wt^T  (bf16 MFMA 16x16x32) ----
__global__ __launch_bounds__(256) void k_gemm(const unsigned short* __restrict__ A,
                                              const unsigned short* __restrict__ Bt,
                                              float* __restrict__ C){
  __shared__ unsigned short As[64 * 72];
  __shared__ unsigned short Bs[64 * 72];
  int m0 = blockIdx.x * 64, n0 = blockIdx.y * 64;
  int t = threadIdx.x;
  int lane = t & 63, w = t >> 6;
  int wrow = (w & 1) * 32, wcol = (w >> 1) * 32;  // wave's 32x32 quadrant
  int r16  = lane & 15;                           // row/col within 16-tile
  int quad = lane >> 4;                           // k-subchunk (quad*8)

  f32x4 acc[2][2];
  #pragma unroll
  for (int p = 0; p < 2; ++p)
    #pragma unroll
    for (int q = 0; q < 2; ++q)
      #pragma unroll
      for (int e = 0; e < 4; ++e) acc[p][q][e] = 0.f;

  for (int kt = 0; kt < 1024; kt += 64){
    // stage 64x64 bf16 tiles of A and Bt (contiguous-k rows)
    #pragma unroll
    for (int q = t; q < 512; q += 256){
      int row = q >> 3, c8 = q & 7;
      *(uint4*)(&As[row * 72 + c8 * 8]) = *(const uint4*)(A  + (size_t)(m0 + row) * 1024 + kt + c8 * 8);
      *(uint4*)(&Bs[row * 72 + c8 * 8]) = *(const uint4*)(Bt + (size_t)(n0 + row) * 1024 + kt + c8 * 8);
    }
    __syncthreads();
    #pragma unroll
    for (int kk = 0; kk < 2; ++kk){               // two K=32 steps
      int ko = kk * 32 + quad * 8;
      bf16x8 a0 = *(const bf16x8*)(&As[(wrow      + r16) * 72 + ko]);
      bf16x8 a1 = *(const bf16x8*)(&As[(wrow + 16 + r16) * 72 + ko]);
      bf16x8 b0 = *(const bf16x8*)(&Bs[(wcol      + r16) * 72 + ko]);
      bf16x8 b1 = *(const bf16x8*)(&Bs[(wcol + 16 + r16) * 72 + ko]);
      acc[0][0] = __builtin_amdgcn_mfma_f32_16x16x32_bf16(a0, b0, acc[0][0], 0, 0, 0);
      acc[0][1] = __builtin_amdgcn_mfma_f32_16x16x32_bf16(a0, b1, acc[0][1], 0, 0, 0);
      acc[1][0] = __builtin_amdgcn_mfma_f32_16x16x32_bf16(a1, b0, acc[1][0], 0, 0, 0);
      acc[1][1] = __builtin_amdgcn_mfma_f32_16x16x32_bf16(a1, b1, acc[1][1], 0, 0, 0);
    }
    __syncthreads();
  }
  // C/D layout (m89/m91 verified): col = lane&15, row = (lane>>4)*4 + reg
  #pragma unroll
  for (int p = 0; p < 2; ++p)
    #pragma unroll
    for (int q = 0; q < 2; ++q)
      #pragma unroll
      for (int r = 0; r < 4; ++r){
        int row = m0 + wrow + p * 16 + quad * 4 + r;
        int col = n0 + wcol + q * 16 + r16;
        C[(size_t)row * 1024 + col] = acc[p][q][r];
      }
}

// ---- K2: out[j][b] = bias[b] + sum_i exp(-sum_c |mat[i,b,c]-mat[j,b,c]|) ----
// grid 256 = 64 b * 4 j-chunks; 512 threads = 8 waves; wave w owns i in [w*32, w*32+32)
__global__ __launch_bounds__(512) void k_pair(const float* __restrict__ mat,
                                              const float* __restrict__ bias,
                                              float* __restrict__ out){
  __shared__ float red[8][64];
  int b  = blockIdx.x >> 2;
  int jc = blockIdx.x & 3;
  int t = threadIdx.x;
  int lane = t & 63, w = t >> 6;
  int j = jc * 64 + lane;

  // own j-row, pre-scaled by log2(e) so exp(-l1) == exp2(-l1')
  const float* jr = mat + (size_t)j * 1024 + b * 16;
  float oj[16];
  #pragma unroll
  for (int c4 = 0; c4 < 4; ++c4){
    float4 v = *(const float4*)(jr + c4 * 4);
    oj[c4*4+0] = v.x * LOG2E; oj[c4*4+1] = v.y * LOG2E;
    oj[c4*4+2] = v.z * LOG2E; oj[c4*4+3] = v.w * LOG2E;
  }
  // own i-row (lanes 0..31 carry the wave's 32 i-rows; 32..63 duplicate, unused by readlane)
  int i0 = w * 32 + (lane & 31);
  const float* ir = mat + (size_t)i0 * 1024 + b * 16;
  float oi[16];
  #pragma unroll
  for (int c4 = 0; c4 < 4; ++c4){
    float4 v = *(const float4*)(ir + c4 * 4);
    oi[c4*4+0] = v.x * LOG2E; oi[c4*4+1] = v.y * LOG2E;
    oi[c4*4+2] = v.z * LOG2E; oi[c4*4+3] = v.w * LOG2E;
  }

  float acc = 0.f;
  for (int ii = 0; ii < 32; ++ii){
    float p0 = 0.f, p1 = 0.f, p2 = 0.f, p3 = 0.f;   // 4 chains to hide VALU latency
    #pragma unroll
    for (int c = 0; c < 16; c += 4){
      float b0 = __uint_as_float(__builtin_amdgcn_readlane(__float_as_uint(oi[c+0]), ii));
      float b1 = __uint_as_float(__builtin_amdgcn_readlane(__float_as_uint(oi[c+1]), ii));
      float b2 = __uint_as_float(__builtin_amdgcn_readlane(__float_as_uint(oi[c+2]), ii));
      float b3 = __uint_as_float(__builtin_amdgcn_readlane(__float_as_uint(oi[c+3]), ii));
      p0 += fabsf(oj[c+0] - b0);
      p1 += fabsf(oj[c+1] - b1);
      p2 += fabsf(oj[c+2] - b2);
      p3 += fabsf(oj[c+3] - b3);
    }
    acc += exp2f(-((p0 + p1) + (p2 + p3)));
  }
  red[w][lane] = acc;
  __syncthreads();
  if (w == 0){
    float tot = 0.f;
    #pragma unroll
    for (int ww = 0; ww < 8; ++ww) tot += red[ww][lane];
    out[(size_t)j * 64 + b] = tot + bias[b];
  }
}

extern "C" void kernel_launch(void* const* d_in, const int* in_sizes, int n_in,
                              void* d_out, int out_size, void* d_ws, size_t ws_size,
                              hipStream_t stream){
  const float* x    = (const float*)d_in[0];   // [256][1024]
  const float* W    = (const float*)d_in[1];   // [1024][1024]
  const float* bias = (const float*)d_in[2];   // [64]
  float* out = (float*)d_out;                  // [256][64]

  unsigned short* xb  = (unsigned short*)d_ws;       // 512 KB bf16 x
  unsigned short* Wt  = xb + 256 * 1024;             // 2 MB bf16 W^T [N][K]
  float*          mat = (float*)(Wt + 1024 * 1024);  // 1 MB f32 mat [256][1024]

  k_cvt_x<<<128, 256, 0, stream>>>(x, xb);
  k_tr_w<<<dim3(16, 16), 256, 0, stream>>>(W, Wt);
  k_gemm<<<dim3(4, 16), 256, 0, stream>>>(xb, Wt, mat);
  k_pair<<<256, 512, 0, stream>>>(mat, bias, out);
}

// Round 2
// 83.350 us; speedup vs baseline: 1.0881x; 1.0881x over previous
//
#include <hip/hip_runtime.h>

#define LOG2E 1.4426950408889634f

typedef __bf16 bf16x8 __attribute__((ext_vector_type(8)));
typedef float  f32x4  __attribute__((ext_vector_type(4)));

__device__ inline unsigned short f2bf(float f){
  unsigned u = __float_as_uint(f);
  unsigned r = u + 0x7FFFu + ((u >> 16) & 1u);   // RNE; inputs finite
  return (unsigned short)(r >> 16);
}
__device__ inline unsigned pack2(float lo, float hi){
  return (unsigned)f2bf(lo) | ((unsigned)f2bf(hi) << 16);
}

// ---- K1: mat[256][1024] f32 = x[256][1024]f32 @ W[1024][1024]f32 (k-major)
// f32->bf16 convert + W transpose fused into LDS staging; reg double-buffer.
// grid (4 m-tiles, 16 n-tiles) = 64 blocks, 256 thr.
__global__ __launch_bounds__(256) void k_gemm_fused(const float* __restrict__ X,
                                                    const float* __restrict__ Wm,
                                                    float* __restrict__ mat){
  __shared__ unsigned short As[64 * 72];   // [m][k] bf16, row stride 72 (16B-aligned)
  __shared__ unsigned short Bs[64 * 72];   // [n][k] bf16, XOR-chunk swizzled
  const int m0 = blockIdx.x * 64, n0 = blockIdx.y * 64;
  const int t = threadIdx.x;
  const int lane = t & 63, w = t >> 6;
  const int wrow = (w & 1) * 32, wcol = (w >> 1) * 32;
  const int r16 = lane & 15, quad = lane >> 4;

  // staging maps
  const int ar = t >> 2, aq = t & 3;          // A: row 0..63, 16-float quarter
  const int bc = t & 15, bg = t >> 4;         // B: 4-col group, 4-krow group
  const float* ap = X + (size_t)(m0 + ar) * 1024 + aq * 16;
  const float* bp = Wm + n0 + bc * 4;

  f32x4 acc[2][2];
  #pragma unroll
  for (int p = 0; p < 2; ++p)
    #pragma unroll
    for (int q = 0; q < 2; ++q)
      #pragma unroll
      for (int e = 0; e < 4; ++e) acc[p][q][e] = 0.f;

  float4 pa[4], pb[4];
  #pragma unroll
  for (int r = 0; r < 4; ++r) pa[r] = *(const float4*)(ap + r * 4);
  #pragma unroll
  for (int r = 0; r < 4; ++r) pb[r] = *(const float4*)(bp + (size_t)(4 * bg + r) * 1024);

  for (int kt = 0; kt < 1024; kt += 64){
    __syncthreads();                          // prev iter's ds_reads done
    { // A tile: convert 16 floats -> 16 bf16, contiguous store (conflict-free)
      unsigned short* d = &As[ar * 72 + aq * 16];
      uint4 o;
      o.x = pack2(pa[0].x, pa[0].y); o.y = pack2(pa[0].z, pa[0].w);
      o.z = pack2(pa[1].x, pa[1].y); o.w = pack2(pa[1].z, pa[1].w);
      *(uint4*)d = o;
      o.x = pack2(pa[2].x, pa[2].y); o.y = pack2(pa[2].z, pa[2].w);
      o.z = pack2(pa[3].x, pa[3].y); o.w = pack2(pa[3].z, pa[3].w);
      *(uint4*)(d + 8) = o;
    }
    { // B tile: transpose 4 k-rows x 4 n-cols into [n][k], swizzled chunks
      #pragma unroll
      for (int e = 0; e < 4; ++e){
        const int n = bc * 4 + e;
        uint2 o;
        o.x = pack2(((const float*)&pb[0])[e], ((const float*)&pb[1])[e]);
        o.y = pack2(((const float*)&pb[2])[e], ((const float*)&pb[3])[e]);
        const int cw = (bg >> 1) ^ ((n >> 3) & 7);      // 8-bf16 chunk swizzle
        *(uint2*)(&Bs[n * 72 + cw * 8 + (bg & 1) * 4]) = o;
      }
    }
    __syncthreads();
    if (kt + 64 < 1024){                      // prefetch next tiles into regs
      #pragma unroll
      for (int r = 0; r < 4; ++r) pa[r] = *(const float4*)(ap + kt + 64 + r * 4);
      #pragma unroll
      for (int r = 0; r < 4; ++r) pb[r] = *(const float4*)(bp + (size_t)(kt + 64 + 4 * bg + r) * 1024);
    }
    #pragma unroll
    for (int kk = 0; kk < 2; ++kk){
      const int ko = kk * 32 + quad * 8;
      bf16x8 a0 = *(const bf16x8*)(&As[(wrow      + r16) * 72 + ko]);
      bf16x8 a1 = *(const bf16x8*)(&As[(wrow + 16 + r16) * 72 + ko]);
      const int c = kk * 4 + quad;
      const int nb0 = wcol + r16, nb1 = wcol + 16 + r16;
      bf16x8 b0 = *(const bf16x8*)(&Bs[nb0 * 72 + ((c ^ ((nb0 >> 3) & 7)) * 8)]);
      bf16x8 b1 = *(const bf16x8*)(&Bs[nb1 * 72 + ((c ^ ((nb1 >> 3) & 7)) * 8)]);
      acc[0][0] = __builtin_amdgcn_mfma_f32_16x16x32_bf16(a0, b0, acc[0][0], 0, 0, 0);
      acc[0][1] = __builtin_amdgcn_mfma_f32_16x16x32_bf16(a0, b1, acc[0][1], 0, 0, 0);
      acc[1][0] = __builtin_amdgcn_mfma_f32_16x16x32_bf16(a1, b0, acc[1][0], 0, 0, 0);
      acc[1][1] = __builtin_amdgcn_mfma_f32_16x16x32_bf16(a1, b1, acc[1][1], 0, 0, 0);
    }
  }
  // C/D layout (verified): col = lane&15, row = (lane>>4)*4 + reg
  #pragma unroll
  for (int p = 0; p < 2; ++p)
    #pragma unroll
    for (int q = 0; q < 2; ++q)
      #pragma unroll
      for (int r = 0; r < 4; ++r){
        const int row = m0 + wrow + p * 16 + quad * 4 + r;
        const int col = n0 + wcol + q * 16 + r16;
        mat[(size_t)row * 1024 + col] = acc[p][q][r];
      }
}

// ---- K2: out[j][b] = bias[b] + sum_i exp(-sum_c |mat[i,b,c]-mat[j,b,c]|)
// grid 256 = 64 b * 4 j-chunks; 512 thr = 8 waves; wave w owns ii in [w*32,+32).
// i-rows broadcast from LDS (same-addr ds_read_b128 = conflict-free, off the VALU pipe).
__global__ __launch_bounds__(512) void k_pair(const float* __restrict__ mat,
                                              const float* __restrict__ bias,
                                              float* __restrict__ out){
  __shared__ float L[256 * 16];     // mat[:, b*16 .. b*16+16)
  __shared__ float red[8][64];
  const int b = blockIdx.x >> 2, jc = blockIdx.x & 3;
  const int t = threadIdx.x, lane = t & 63, w = t >> 6;

  #pragma unroll
  for (int p = 0; p < 2; ++p){
    const int f = t + p * 512;              // 0..1023 float4 slots
    const int i = f >> 2, q = f & 3;
    *(float4*)(&L[i * 16 + q * 4]) =
        *(const float4*)(mat + (size_t)i * 1024 + b * 16 + q * 4);
  }
  __syncthreads();

  const int j = jc * 64 + lane;
  float oj[16];
  #pragma unroll
  for (int q = 0; q < 4; ++q){
    float4 v = *(const float4*)(&L[j * 16 + q * 4]);
    oj[q*4+0] = v.x; oj[q*4+1] = v.y; oj[q*4+2] = v.z; oj[q*4+3] = v.w;
  }

  float acc = 0.f;
  const int i0 = w * 32;
  for (int ii = i0; ii < i0 + 32; ++ii){
    const float4* fr = (const float4*)(&L[ii * 16]);   // wave-uniform -> broadcast
    float4 f0 = fr[0], f1 = fr[1], f2 = fr[2], f3 = fr[3];
    float p0 = fabsf(oj[0]  - f0.x) + fabsf(oj[1]  - f0.y)
             + fabsf(oj[2]  - f0.z) + fabsf(oj[3]  - f0.w);
    float p1 = fabsf(oj[4]  - f1.x) + fabsf(oj[5]  - f1.y)
             + fabsf(oj[6]  - f1.z) + fabsf(oj[7]  - f1.w);
    float p2 = fabsf(oj[8]  - f2.x) + fabsf(oj[9]  - f2.y)
             + fabsf(oj[10] - f2.z) + fabsf(oj[11] - f2.w);
    float p3 = fabsf(oj[12] - f3.x) + fabsf(oj[13] - f3.y)
             + fabsf(oj[14] - f3.z) + fabsf(oj[15] - f3.w);
    acc += exp2f(-LOG2E * ((p0 + p1) + (p2 + p3)));
  }
  red[w][lane] = acc;
  __syncthreads();
  if (w == 0){
    float tot = 0.f;
    #pragma unroll
    for (int ww = 0; ww < 8; ++ww) tot += red[ww][lane];
    out[(size_t)j * 64 + b] = tot + bias[b];
  }
}

extern "C" void kernel_launch(void* const* d_in, const int* in_sizes, int n_in,
                              void* d_out, int out_size, void* d_ws, size_t ws_size,
                              hipStream_t stream){
  const float* x    = (const float*)d_in[0];   // [256][1024]
  const float* W    = (const float*)d_in[1];   // [1024][1024] k-major
  const float* bias = (const float*)d_in[2];   // [64]
  float* out = (float*)d_out;                  // [256][64]
  float* mat = (float*)d_ws;                   // 1 MB f32 scratch

  k_gemm_fused<<<dim3(4, 16), 256, 0, stream>>>(x, W, mat);
  k_pair<<<256, 512, 0, stream>>>(mat, bias, out);
}

// Round 3
// 76.732 us; speedup vs baseline: 1.1820x; 1.0862x over previous
//
#include <hip/hip_runtime.h>

#define LOG2E 1.4426950408889634f

typedef __bf16 bf16x8 __attribute__((ext_vector_type(8)));
typedef float  f32x4  __attribute__((ext_vector_type(4)));

__device__ inline unsigned short f2bf(float f){
  unsigned u = __float_as_uint(f);
  unsigned r = u + 0x7FFFu + ((u >> 16) & 1u);   // RNE; inputs finite
  return (unsigned short)(r >> 16);
}
__device__ inline unsigned pack2(float lo, float hi){
  return (unsigned)f2bf(lo) | ((unsigned)f2bf(hi) << 16);
}

// ---- K1: K-split GEMM.  P[ks][256][1024] f32 partial = x[:, ks*256:+256] @ W[ks*256:+256, :]
// grid (4 m-tiles, 16 n-tiles, 4 k-splits) = 256 blocks (1/CU), 256 thr.
// f32->bf16 convert + W transpose fused into LDS staging; reg prefetch 1 iter ahead.
__global__ __launch_bounds__(256) void k_gemm_ks(const float* __restrict__ X,
                                                 const float* __restrict__ Wm,
                                                 float* __restrict__ P){
  __shared__ unsigned short As[64 * 72];   // [m][k] bf16, row stride 72
  __shared__ unsigned short Bs[64 * 72];   // [n][k] bf16, XOR-chunk swizzled
  const int m0 = blockIdx.x * 64, n0 = blockIdx.y * 64;
  const int k0 = blockIdx.z * 256;
  const int t = threadIdx.x;
  const int lane = t & 63, w = t >> 6;
  const int wrow = (w & 1) * 32, wcol = (w >> 1) * 32;
  const int r16 = lane & 15, quad = lane >> 4;

  const int ar = t >> 2, aq = t & 3;          // A: row 0..63, 16-float quarter
  const int bc = t & 15, bg = t >> 4;         // B: 4-col group, 4-krow group
  const float* ap = X + (size_t)(m0 + ar) * 1024 + k0 + aq * 16;
  const float* bp = Wm + (size_t)k0 * 1024 + n0 + bc * 4;

  f32x4 acc[2][2];
  #pragma unroll
  for (int p = 0; p < 2; ++p)
    #pragma unroll
    for (int q = 0; q < 2; ++q)
      #pragma unroll
      for (int e = 0; e < 4; ++e) acc[p][q][e] = 0.f;

  float4 pa[4], pb[4];
  #pragma unroll
  for (int r = 0; r < 4; ++r) pa[r] = *(const float4*)(ap + r * 4);
  #pragma unroll
  for (int r = 0; r < 4; ++r) pb[r] = *(const float4*)(bp + (size_t)(4 * bg + r) * 1024);

  #pragma unroll
  for (int kt = 0; kt < 256; kt += 64){
    __syncthreads();                          // prev iter's ds_reads done
    { // A tile: 16 floats -> 16 bf16, contiguous store
      unsigned short* d = &As[ar * 72 + aq * 16];
      uint4 o;
      o.x = pack2(pa[0].x, pa[0].y); o.y = pack2(pa[0].z, pa[0].w);
      o.z = pack2(pa[1].x, pa[1].y); o.w = pack2(pa[1].z, pa[1].w);
      *(uint4*)d = o;
      o.x = pack2(pa[2].x, pa[2].y); o.y = pack2(pa[2].z, pa[2].w);
      o.z = pack2(pa[3].x, pa[3].y); o.w = pack2(pa[3].z, pa[3].w);
      *(uint4*)(d + 8) = o;
    }
    { // B tile: transpose 4 k-rows x 4 n-cols into [n][k], swizzled 8-bf16 chunks
      #pragma unroll
      for (int e = 0; e < 4; ++e){
        const int n = bc * 4 + e;
        uint2 o;
        o.x = pack2(((const float*)&pb[0])[e], ((const float*)&pb[1])[e]);
        o.y = pack2(((const float*)&pb[2])[e], ((const float*)&pb[3])[e]);
        const int cw = (bg >> 1) ^ ((n >> 3) & 7);
        *(uint2*)(&Bs[n * 72 + cw * 8 + (bg & 1) * 4]) = o;
      }
    }
    __syncthreads();
    if (kt < 192){                            // prefetch next k-tile into regs
      #pragma unroll
      for (int r = 0; r < 4; ++r) pa[r] = *(const float4*)(ap + kt + 64 + r * 4);
      #pragma unroll
      for (int r = 0; r < 4; ++r) pb[r] = *(const float4*)(bp + (size_t)(kt + 64 + 4 * bg + r) * 1024);
    }
    #pragma unroll
    for (int kk = 0; kk < 2; ++kk){
      const int ko = kk * 32 + quad * 8;
      bf16x8 a0 = *(const bf16x8*)(&As[(wrow      + r16) * 72 + ko]);
      bf16x8 a1 = *(const bf16x8*)(&As[(wrow + 16 + r16) * 72 + ko]);
      const int c = kk * 4 + quad;
      const int nb0 = wcol + r16, nb1 = wcol + 16 + r16;
      bf16x8 b0 = *(const bf16x8*)(&Bs[nb0 * 72 + ((c ^ ((nb0 >> 3) & 7)) * 8)]);
      bf16x8 b1 = *(const bf16x8*)(&Bs[nb1 * 72 + ((c ^ ((nb1 >> 3) & 7)) * 8)]);
      acc[0][0] = __builtin_amdgcn_mfma_f32_16x16x32_bf16(a0, b0, acc[0][0], 0, 0, 0);
      acc[0][1] = __builtin_amdgcn_mfma_f32_16x16x32_bf16(a0, b1, acc[0][1], 0, 0, 0);
      acc[1][0] = __builtin_amdgcn_mfma_f32_16x16x32_bf16(a1, b0, acc[1][0], 0, 0, 0);
      acc[1][1] = __builtin_amdgcn_mfma_f32_16x16x32_bf16(a1, b1, acc[1][1], 0, 0, 0);
    }
  }
  // C/D layout (verified): col = lane&15, row = (lane>>4)*4 + reg
  float* Pz = P + (size_t)blockIdx.z * 256 * 1024;
  #pragma unroll
  for (int p = 0; p < 2; ++p)
    #pragma unroll
    for (int q = 0; q < 2; ++q)
      #pragma unroll
      for (int r = 0; r < 4; ++r){
        const int row = m0 + wrow + p * 16 + quad * 4 + r;
        const int col = n0 + wcol + q * 16 + r16;
        Pz[(size_t)row * 1024 + col] = acc[p][q][r];
      }
}

// ---- K2: out[j][b] = bias[b] + sum_i exp(-sum_c |mat[i,b,c]-mat[j,b,c]|)
// grid 256 = 64 b * 4 j-chunks; 1024 thr = 16 waves (4/SIMD); wave w owns i in [w*16,+16).
// Staging sums the 4 K-split partials; i-rows broadcast via same-addr ds_read_b128.
__global__ __launch_bounds__(1024) void k_pair(const float* __restrict__ P,
                                               const float* __restrict__ bias,
                                               float* __restrict__ out){
  __shared__ float L[256 * 16];     // mat[:, b*16 .. b*16+16)
  __shared__ float red[16][64];
  const int b = blockIdx.x >> 2, jc = blockIdx.x & 3;
  const int t = threadIdx.x, lane = t & 63, w = t >> 6;

  { // stage + reduce K-split partials: thread -> one float4 of L
    const int i = t >> 2, q = t & 3;
    const float* base = P + (size_t)i * 1024 + b * 16 + q * 4;
    float4 s0 = *(const float4*)(base);
    float4 s1 = *(const float4*)(base + 256 * 1024);
    float4 s2 = *(const float4*)(base + 512 * 1024);
    float4 s3 = *(const float4*)(base + 768 * 1024);
    float4 r;
    r.x = (s0.x + s1.x) + (s2.x + s3.x);
    r.y = (s0.y + s1.y) + (s2.y + s3.y);
    r.z = (s0.z + s1.z) + (s2.z + s3.z);
    r.w = (s0.w + s1.w) + (s2.w + s3.w);
    *(float4*)(&L[i * 16 + q * 4]) = r;
  }
  __syncthreads();

  const int j = jc * 64 + lane;
  float oj[16];
  #pragma unroll
  for (int q = 0; q < 4; ++q){
    float4 v = *(const float4*)(&L[j * 16 + q * 4]);
    oj[q*4+0] = v.x; oj[q*4+1] = v.y; oj[q*4+2] = v.z; oj[q*4+3] = v.w;
  }

  float acc = 0.f;
  const int i0 = w * 16;
  #pragma unroll 4
  for (int ii = i0; ii < i0 + 16; ++ii){
    const float4* fr = (const float4*)(&L[ii * 16]);   // wave-uniform -> broadcast
    float4 f0 = fr[0], f1 = fr[1], f2 = fr[2], f3 = fr[3];
    float p0 = fabsf(oj[0]  - f0.x) + fabsf(oj[1]  - f0.y)
             + fabsf(oj[2]  - f0.z) + fabsf(oj[3]  - f0.w);
    float p1 = fabsf(oj[4]  - f1.x) + fabsf(oj[5]  - f1.y)
             + fabsf(oj[6]  - f1.z) + fabsf(oj[7]  - f1.w);
    float p2 = fabsf(oj[8]  - f2.x) + fabsf(oj[9]  - f2.y)
             + fabsf(oj[10] - f2.z) + fabsf(oj[11] - f2.w);
    float p3 = fabsf(oj[12] - f3.x) + fabsf(oj[13] - f3.y)
             + fabsf(oj[14] - f3.z) + fabsf(oj[15] - f3.w);
    acc += exp2f(-LOG2E * ((p0 + p1) + (p2 + p3)));
  }
  red[w][lane] = acc;
  __syncthreads();
  if (w == 0){
    float tot = 0.f;
    #pragma unroll
    for (int ww = 0; ww < 16; ++ww) tot += red[ww][lane];
    out[(size_t)j * 64 + b] = tot + bias[b];
  }
}

extern "C" void kernel_launch(void* const* d_in, const int* in_sizes, int n_in,
                              void* d_out, int out_size, void* d_ws, size_t ws_size,
                              hipStream_t stream){
  const float* x    = (const float*)d_in[0];   // [256][1024]
  const float* W    = (const float*)d_in[1];   // [1024][1024] k-major
  const float* bias = (const float*)d_in[2];   // [64]
  float* out = (float*)d_out;                  // [256][64]
  float* P   = (float*)d_ws;                   // 4 MB: partial [4][256][1024]

  k_gemm_ks<<<dim3(4, 16, 4), 256, 0, stream>>>(x, W, P);
  k_pair<<<256, 1024, 0, stream>>>(P, bias, out);
}